// Round 1
// baseline (203.226 us; speedup 1.0000x reference)
//
#include <hip/hip_runtime.h>

// Problem constants (from reference setup_inputs):
//   feats: [B, S, H] float32, segment_ids: [B, S] int32 sorted non-decreasing,
//   values in [0, G). Outputs: grouped [B, G, H] f32, counts [B, G] (written as
//   float values into the flat f32 out buffer, concatenated after grouped).
#define BB 8
#define SS 8192
#define HH 512
#define GG 1024

// One block per (group g, batch b). Sorted ids => each group is a contiguous
// token range [lo, hi). All 128 lanes do the same binary searches (uniform
// control flow, broadcast cached loads), then each lane owns one float4 column
// (128 lanes * 16B = 2048B = full H row, perfectly coalesced per token).
__global__ __launch_bounds__(128) void group_mean_kernel(
    const float* __restrict__ feats,
    const int*   __restrict__ ids,
    float*       __restrict__ grouped,
    float*       __restrict__ counts)
{
    const int g = blockIdx.x;   // group index [0, G)
    const int b = blockIdx.y;   // batch index [0, B)
    const int t = threadIdx.x;  // 0..127, owns float4 column t

    const int* __restrict__ row = ids + (size_t)b * SS;

    // lower_bound(row, row+S, val)
    int lo = 0, hi = SS;
    {
        int l = 0, h = SS;
        while (l < h) { int m = (l + h) >> 1; if (row[m] < g)     l = m + 1; else h = m; }
        lo = l;
        l = lo; h = SS;
        while (l < h) { int m = (l + h) >> 1; if (row[m] < g + 1) l = m + 1; else h = m; }
        hi = l;
    }
    const int count = hi - lo;

    const float4* __restrict__ f4 = (const float4*)(feats + (size_t)b * SS * HH);
    float4 acc = make_float4(0.f, 0.f, 0.f, 0.f);
    for (int s = lo; s < hi; ++s) {
        float4 v = f4[(size_t)s * (HH / 4) + t];
        acc.x += v.x; acc.y += v.y; acc.z += v.z; acc.w += v.w;
    }
    const float inv = (count > 0) ? (1.0f / (float)count) : 0.0f;
    acc.x *= inv; acc.y *= inv; acc.z *= inv; acc.w *= inv;

    ((float4*)(grouped + ((size_t)b * GG + g) * HH))[t] = acc;
    if (t == 0) counts[(size_t)b * GG + g] = (float)count;
}

extern "C" void kernel_launch(void* const* d_in, const int* in_sizes, int n_in,
                              void* d_out, int out_size, void* d_ws, size_t ws_size,
                              hipStream_t stream) {
    const float* feats = (const float*)d_in[0];
    const int*   ids   = (const int*)d_in[1];
    float* grouped = (float*)d_out;
    float* counts  = grouped + (size_t)BB * GG * HH;  // second tuple output, flat-concat

    dim3 grid(GG, BB);
    dim3 block(128);
    group_mean_kernel<<<grid, block, 0, stream>>>(feats, ids, grouped, counts);
}

// Round 2
// 199.845 us; speedup vs baseline: 1.0169x; 1.0169x over previous
//
#include <hip/hip_runtime.h>

// Segment mean-pooling: feats [B,S,H] f32, segment_ids [B,S] i32 sorted
// non-decreasing in [0,G). Outputs flat-concat: grouped [B,G,H] f32, then
// counts [B,G] written as float values.
#define BB 8
#define SS 8192
#define HH 512
#define GG 1024

// Kernel A: offsets[b][g] = lower_bound(ids[b], g) for g in [0, G].
// Sorted ids => each offset written exactly once by the token at the boundary.
// One thread per (b, s). d_ws is poisoned 0xAA, so we must write every slot.
__global__ __launch_bounds__(256) void seg_offsets_kernel(
    const int* __restrict__ ids,
    int*       __restrict__ offsets)   // [B][G+1]
{
    const int tid = blockIdx.x * 256 + threadIdx.x;  // 0 .. B*S-1
    const int b = tid / SS;
    const int s = tid - b * SS;
    const int* __restrict__ row = ids + (size_t)b * SS;
    int* __restrict__ offs = offsets + (size_t)b * (GG + 1);

    const int cur  = row[s];
    const int prev = (s > 0) ? row[s - 1] : -1;
    // all group starts in (prev, cur] begin at s
    for (int g = prev + 1; g <= cur; ++g) offs[g] = s;
    if (s == SS - 1) {
        for (int g = cur + 1; g <= GG; ++g) offs[g] = SS;
    }
}

// Kernel B: one block per (b, g). lo/hi from precomputed offsets (2 loads,
// no dependent-chain binary search). Each of 128 lanes owns one float4
// column (128*16B = 2048B = full H row, perfectly coalesced). Unroll x2
// for memory-level parallelism.
__global__ __launch_bounds__(128) void group_mean_kernel(
    const float* __restrict__ feats,
    const int*   __restrict__ offsets,
    float*       __restrict__ grouped,
    float*       __restrict__ counts)
{
    const int g = blockIdx.x;
    const int b = blockIdx.y;
    const int t = threadIdx.x;  // 0..127

    const int* __restrict__ offs = offsets + (size_t)b * (GG + 1);
    const int lo = offs[g];
    const int hi = offs[g + 1];
    const int count = hi - lo;

    const float4* __restrict__ f4 = (const float4*)(feats + (size_t)b * SS * HH);
    float4 a0 = make_float4(0.f, 0.f, 0.f, 0.f);
    float4 a1 = make_float4(0.f, 0.f, 0.f, 0.f);
    int s = lo;
    for (; s + 1 < hi; s += 2) {
        float4 v0 = f4[(size_t)s       * (HH / 4) + t];
        float4 v1 = f4[(size_t)(s + 1) * (HH / 4) + t];
        a0.x += v0.x; a0.y += v0.y; a0.z += v0.z; a0.w += v0.w;
        a1.x += v1.x; a1.y += v1.y; a1.z += v1.z; a1.w += v1.w;
    }
    if (s < hi) {
        float4 v0 = f4[(size_t)s * (HH / 4) + t];
        a0.x += v0.x; a0.y += v0.y; a0.z += v0.z; a0.w += v0.w;
    }
    const float inv = (count > 0) ? (1.0f / (float)count) : 0.0f;
    float4 r;
    r.x = (a0.x + a1.x) * inv;
    r.y = (a0.y + a1.y) * inv;
    r.z = (a0.z + a1.z) * inv;
    r.w = (a0.w + a1.w) * inv;

    ((float4*)(grouped + ((size_t)b * GG + g) * HH))[t] = r;
    if (t == 0) counts[(size_t)b * GG + g] = (float)count;
}

extern "C" void kernel_launch(void* const* d_in, const int* in_sizes, int n_in,
                              void* d_out, int out_size, void* d_ws, size_t ws_size,
                              hipStream_t stream) {
    const float* feats = (const float*)d_in[0];
    const int*   ids   = (const int*)d_in[1];
    float* grouped = (float*)d_out;
    float* counts  = grouped + (size_t)BB * GG * HH;
    int*   offsets = (int*)d_ws;   // B*(G+1) ints

    seg_offsets_kernel<<<(BB * SS) / 256, 256, 0, stream>>>(ids, offsets);
    dim3 grid(GG, BB);
    group_mean_kernel<<<grid, 128, 0, stream>>>(feats, offsets, grouped, counts);
}

// Round 3
// 189.444 us; speedup vs baseline: 1.0727x; 1.0549x over previous
//
#include <hip/hip_runtime.h>

// Segment mean-pooling: feats [B,S,H] f32, segment_ids [B,S] i32 sorted
// non-decreasing in [0,G). Outputs flat-concat: grouped [B,G,H] f32, then
// counts [B,G] written as float values.
#define BB 8
#define SS 8192
#define HH 512
#define GG 1024
#define GPB 4   // groups per block

typedef float f32x4 __attribute__((ext_vector_type(4)));

// Kernel A: offsets[b][g] = lower_bound(ids[b], g) for g in [0, G].
// Sorted ids => each offset written exactly once (boundary token writes it).
__global__ __launch_bounds__(256) void seg_offsets_kernel(
    const int* __restrict__ ids,
    int*       __restrict__ offsets)   // [B][G+1]
{
    const int tid = blockIdx.x * 256 + threadIdx.x;  // 0 .. B*S-1
    const int b = tid / SS;
    const int s = tid - b * SS;
    const int* __restrict__ row = ids + (size_t)b * SS;
    int* __restrict__ offs = offsets + (size_t)b * (GG + 1);

    const int cur  = row[s];
    const int prev = (s > 0) ? row[s - 1] : -1;
    for (int g = prev + 1; g <= cur; ++g) offs[g] = s;
    if (s == SS - 1) {
        for (int g = cur + 1; g <= GG; ++g) offs[g] = SS;
    }
}

// Kernel B: one block per (b, 4 consecutive groups). 128 lanes * float4 =
// 2048B = full H row, perfectly coalesced per token. 4-deep unroll for MLP;
// nontemporal loads/stores (pure streaming, no reuse).
__global__ __launch_bounds__(128) void group_mean_kernel(
    const f32x4* __restrict__ feats,
    const int*   __restrict__ offsets,
    f32x4*       __restrict__ grouped,
    float*       __restrict__ counts)
{
    const int g0 = blockIdx.x * GPB;
    const int b  = blockIdx.y;
    const int t  = threadIdx.x;  // 0..127

    const int* __restrict__ offs = offsets + (size_t)b * (GG + 1) + g0;
    int o[GPB + 1];
    #pragma unroll
    for (int i = 0; i < GPB + 1; ++i) o[i] = offs[i];

    const f32x4* __restrict__ fb = feats + (size_t)b * SS * (HH / 4);

    #pragma unroll
    for (int i = 0; i < GPB; ++i) {
        const int lo = o[i], hi = o[i + 1];
        const int n = hi - lo;
        f32x4 a0 = 0.f, a1 = 0.f, a2 = 0.f, a3 = 0.f;
        int s = lo;
        for (; s + 3 < hi; s += 4) {
            f32x4 v0 = __builtin_nontemporal_load(&fb[(size_t)(s    ) * (HH / 4) + t]);
            f32x4 v1 = __builtin_nontemporal_load(&fb[(size_t)(s + 1) * (HH / 4) + t]);
            f32x4 v2 = __builtin_nontemporal_load(&fb[(size_t)(s + 2) * (HH / 4) + t]);
            f32x4 v3 = __builtin_nontemporal_load(&fb[(size_t)(s + 3) * (HH / 4) + t]);
            a0 += v0; a1 += v1; a2 += v2; a3 += v3;
        }
        for (; s < hi; ++s) {
            a0 += __builtin_nontemporal_load(&fb[(size_t)s * (HH / 4) + t]);
        }
        const float inv = (n > 0) ? (1.0f / (float)n) : 0.0f;
        f32x4 r = ((a0 + a1) + (a2 + a3)) * inv;
        __builtin_nontemporal_store(r, &grouped[((size_t)b * GG + g0 + i) * (HH / 4) + t]);
        if (t == 0) counts[(size_t)b * GG + g0 + i] = (float)n;
    }
}

extern "C" void kernel_launch(void* const* d_in, const int* in_sizes, int n_in,
                              void* d_out, int out_size, void* d_ws, size_t ws_size,
                              hipStream_t stream) {
    const float* feats = (const float*)d_in[0];
    const int*   ids   = (const int*)d_in[1];
    float* grouped = (float*)d_out;
    float* counts  = grouped + (size_t)BB * GG * HH;
    int*   offsets = (int*)d_ws;   // B*(G+1) ints

    seg_offsets_kernel<<<(BB * SS) / 256, 256, 0, stream>>>(ids, offsets);
    dim3 grid(GG / GPB, BB);
    group_mean_kernel<<<grid, 128, 0, stream>>>((const f32x4*)feats, offsets,
                                                (f32x4*)grouped, counts);
}